// Round 5
// baseline (2559.124 us; speedup 1.0000x reference)
//
#include <hip/hip_runtime.h>

#define TPB 256

static constexpr int B_ = 4;
static constexpr int DEG_ = 16;

// level bases into the packed count array (sum = 87040 = 85 * 1024)
static constexpr int LB0 = 0, LB1 = 65536, LB2 = 81920, LB3 = 86016, LB4 = 87040;
// cumulative edge counts
static constexpr int CE0 = 0, CE1 = 1048576, CE2 = 1310720, CE3 = 1376256, CE4 = 1392640;

// ---------------- CSR build kernels ----------------

__global__ void cnt_kernel(const int* __restrict__ row, int* __restrict__ cnt, int E) {
    int e = blockIdx.x * blockDim.x + threadIdx.x;
    if (e < E) atomicAdd(&cnt[row[e]], 1);
}

__global__ void scanA_kernel(const int* __restrict__ cnt, int* __restrict__ partial,
                             int* __restrict__ bsum) {
    __shared__ int sdata[256];
    int tid = threadIdx.x;
    int base = blockIdx.x * 1024 + tid * 4;
    int v0 = cnt[base], v1 = cnt[base + 1], v2 = cnt[base + 2], v3 = cnt[base + 3];
    int tsum = v0 + v1 + v2 + v3;
    sdata[tid] = tsum;
    __syncthreads();
    for (int ofs = 1; ofs < 256; ofs <<= 1) {
        int x = (tid >= ofs) ? sdata[tid - ofs] : 0;
        __syncthreads();
        sdata[tid] += x;
        __syncthreads();
    }
    int excl = sdata[tid] - tsum;
    partial[base] = excl;         excl += v0;
    partial[base + 1] = excl;     excl += v1;
    partial[base + 2] = excl;     excl += v2;
    partial[base + 3] = excl;
    if (tid == 255) bsum[blockIdx.x] = sdata[255];
}

__global__ void scanB_kernel(int* __restrict__ bsum, int nb) {
    __shared__ int s[128];
    int tid = threadIdx.x;
    int v = tid < nb ? bsum[tid] : 0;
    s[tid] = v;
    __syncthreads();
    for (int ofs = 1; ofs < 128; ofs <<= 1) {
        int x = (tid >= ofs) ? s[tid - ofs] : 0;
        __syncthreads();
        s[tid] += x;
        __syncthreads();
    }
    if (tid < nb) bsum[tid] = s[tid] - v;
}

__global__ void scanC_kernel(const int* __restrict__ partial, const int* __restrict__ bsum,
                             int* __restrict__ rp0, int* __restrict__ rp1,
                             int* __restrict__ rp2, int* __restrict__ rp3) {
    int i = blockIdx.x * blockDim.x + threadIdx.x;
    if (i >= LB4) return;
    int g = partial[i] + bsum[i >> 10];
    if (i < LB1)      rp0[i - LB0] = g - CE0;
    else if (i < LB2) rp1[i - LB1] = g - CE1;
    else if (i < LB3) rp2[i - LB2] = g - CE2;
    else              rp3[i - LB3] = g - CE3;
    if (i == 0) {
        rp0[LB1 - LB0] = CE1 - CE0;
        rp1[LB2 - LB1] = CE2 - CE1;
        rp2[LB3 - LB2] = CE3 - CE2;
        rp3[LB4 - LB3] = CE4 - CE3;
    }
}

__global__ void fill_kernel(const int* __restrict__ row, const int* __restrict__ col,
                            const int* __restrict__ rowptr, int* __restrict__ cur,
                            const int* __restrict__ cnt, int* __restrict__ ccol,
                            float* __restrict__ cw, int E) {
    int e = blockIdx.x * blockDim.x + threadIdx.x;
    if (e >= E) return;
    int r = row[e], c = col[e];
    int pos = rowptr[r] + atomicAdd(&cur[r], 1);
    float dr = cnt[r] > 0 ? rsqrtf((float)cnt[r]) : 0.f;
    float dc = cnt[c] > 0 ? rsqrtf((float)cnt[c]) : 0.f;
    ccol[pos] = c;
    cw[pos] = dr * dc;
}

// ---------------- fused Chebyshev sweep ----------------
// FIRST:  T1 = L x (gather Tc=x) -> write Tio;  out = x@W0 + T1@W1   (out write-only)
// else:   Tk = 2*L*Tc - Tio_self -> write Tio in place;  out += Tk@Wk
// LAST:   additionally + bias, relu
// XCD-affinity remap: block's XCD ~= blockIdx%8; batch b pinned to XCD pair {2b,2b+1}
// so the per-L2 gather working set is one batch's feature buffer (~4.2 MB at lvl 0).
template<int F, int G, bool FIRST, bool LAST>
__global__ __launch_bounds__(256) void cheb_sweep(
    const float* __restrict__ Tc, float* __restrict__ Tio,
    const int* __restrict__ rowptr, const int* __restrict__ ccol,
    const float* __restrict__ cw, const float* __restrict__ Wk,
    const float* __restrict__ bias, float* __restrict__ out, int N, int relu)
{
    constexpr int WSZ = (FIRST ? 2 : 1) * F * G;
    __shared__ float sW[WSZ];
    for (int i = threadIdx.x; i < WSZ; i += 256) sW[i] = Wk[i];
    __syncthreads();
    // bijective remap: b <- bits{1,2}, within-batch block j <- bits{0,3..}
    int blk = blockIdx.x;
    int b = (blk >> 1) & 3;
    int j = ((blk >> 3) << 1) | (blk & 1);
    int r = j * 256 + (int)threadIdx.x;
    if (r >= N) return;
    int t = b * N + r;
    const float alpha = FIRST ? 1.0f : 2.0f;

    float tv[F];
    if (FIRST) {
        #pragma unroll
        for (int f = 0; f < F; ++f) tv[f] = 0.f;
    } else {
        const float* self = Tio + (size_t)t * F;
        #pragma unroll
        for (int f = 0; f < F; ++f) tv[f] = -self[f];
    }
    const float* base = Tc + (size_t)b * N * F;
    int beg = rowptr[r], end = rowptr[r + 1];
    for (int jj = beg; jj < end; ++jj) {
        int c = __builtin_nontemporal_load(&ccol[jj]);
        float w = alpha * __builtin_nontemporal_load(&cw[jj]);
        const float* src = base + (size_t)c * F;
        if constexpr (F % 4 == 0) {
            #pragma unroll
            for (int f4 = 0; f4 < F / 4; ++f4) {
                float4 v = reinterpret_cast<const float4*>(src)[f4];
                tv[4 * f4 + 0] += w * v.x;
                tv[4 * f4 + 1] += w * v.y;
                tv[4 * f4 + 2] += w * v.z;
                tv[4 * f4 + 3] += w * v.w;
            }
        } else {
            #pragma unroll
            for (int f = 0; f < F; ++f) tv[f] += w * src[f];
        }
    }
    {
        float* dst = Tio + (size_t)t * F;
        #pragma unroll
        for (int f = 0; f < F; ++f) dst[f] = tv[f];
    }

    float acc[G];
    float* orow = out + (size_t)t * G;
    if (FIRST) {
        const float* xs = base + (size_t)r * F;
        #pragma unroll
        for (int g = 0; g < G; ++g) acc[g] = 0.f;
        #pragma unroll
        for (int f = 0; f < F; ++f) {
            float xv = xs[f];
            #pragma unroll
            for (int g = 0; g < G; ++g) acc[g] += xv * sW[f * G + g];
        }
        #pragma unroll
        for (int f = 0; f < F; ++f) {
            float tvf = tv[f];
            #pragma unroll
            for (int g = 0; g < G; ++g) acc[g] += tvf * sW[F * G + f * G + g];
        }
    } else {
        #pragma unroll
        for (int g = 0; g < G; ++g) acc[g] = orow[g];
        #pragma unroll
        for (int f = 0; f < F; ++f) {
            float tvf = tv[f];
            #pragma unroll
            for (int g = 0; g < G; ++g) acc[g] += tvf * sW[f * G + g];
        }
    }
    if (LAST) {
        if (bias) {
            #pragma unroll
            for (int g = 0; g < G; ++g) acc[g] += bias[g];
        }
        if (relu) {
            #pragma unroll
            for (int g = 0; g < G; ++g) acc[g] = fmaxf(acc[g], 0.f);
        }
    }
    #pragma unroll
    for (int g = 0; g < G; ++g) orow[g] = acc[g];
}

// ---------------- pool / dense ----------------

__global__ void pool_kernel(const float* __restrict__ in, float* __restrict__ out,
                            const int* __restrict__ idx, const float* __restrict__ w,
                            int Nin, int Nout, int F) {
    int t = blockIdx.x * blockDim.x + threadIdx.x;
    if (t >= B_ * Nout * F) return;
    int f = t % F;
    int n = (t / F) % Nout;
    int b = t / (F * Nout);
    float acc = 0.f;
    for (int k = 0; k < 3; ++k) {
        int src = idx[n * 3 + k];
        acc += w[n * 3 + k] * in[((size_t)b * Nin + src) * F + f];
    }
    out[((size_t)b * Nout + n) * F + f] = acc;
}

__global__ void dense_enc_kernel(const float* __restrict__ h, const float* __restrict__ W,
                                 const float* __restrict__ bias, float* __restrict__ z) {
    int b = blockIdx.x >> 6;
    int g = blockIdx.x & 63;
    int tid = threadIdx.x;
    float acc = 0.f;
    for (int i = tid; i < 8192; i += 256) acc += h[b * 8192 + i] * W[(size_t)i * 64 + g];
    __shared__ float red[256];
    red[tid] = acc;
    __syncthreads();
    for (int sft = 128; sft > 0; sft >>= 1) {
        if (tid < sft) red[tid] += red[tid + sft];
        __syncthreads();
    }
    if (tid == 0) z[b * 64 + g] = fmaxf(red[0] + bias[g], 0.f);
}

__global__ void dense_dec_kernel(const float* __restrict__ z, const float* __restrict__ W,
                                 const float* __restrict__ bias, float* __restrict__ out) {
    int t = blockIdx.x * blockDim.x + threadIdx.x;
    if (t >= B_ * 8192) return;
    int b = t / 8192, j = t % 8192;
    float acc = bias[j];
    for (int k = 0; k < 64; ++k) acc += z[b * 64 + k] * W[(size_t)k * 8192 + j];
    out[t] = fmaxf(acc, 0.f);
}

// ---------------- host ----------------

static inline unsigned cdivu(size_t a, size_t b) { return (unsigned)((a + b - 1) / b); }

template<int F, int G>
static void run_cheb(const float* Iin, float* I, float* Q, float* out,
                     const float* Wk, const float* bias, int relu,
                     const int* rp, const int* cc, const float* cwp, int N, hipStream_t s) {
    const size_t FG = (size_t)F * G;
    unsigned g = cdivu((size_t)B_ * N, 256);
    cheb_sweep<F, G, true, false><<<g, 256, 0, s>>>(Iin, Q, rp, cc, cwp, Wk, nullptr, out, N, 0);
    cheb_sweep<F, G, false, false><<<g, 256, 0, s>>>(Q, I, rp, cc, cwp, Wk + 2 * FG, nullptr, out, N, 0);
    cheb_sweep<F, G, false, false><<<g, 256, 0, s>>>(I, Q, rp, cc, cwp, Wk + 3 * FG, nullptr, out, N, 0);
    cheb_sweep<F, G, false, false><<<g, 256, 0, s>>>(Q, I, rp, cc, cwp, Wk + 4 * FG, nullptr, out, N, 0);
    cheb_sweep<F, G, false, true><<<g, 256, 0, s>>>(I, Q, rp, cc, cwp, Wk + 5 * FG, bias, out, N, relu);
}

extern "C" void kernel_launch(void* const* d_in, const int* in_sizes, int n_in,
                              void* d_out, int out_size, void* d_ws, size_t ws_size,
                              hipStream_t stream) {
    (void)in_sizes; (void)n_in; (void)out_size; (void)ws_size;
    hipStream_t s = stream;

    static const int NS_[5] = {65536, 16384, 4096, 1024, 256};
    static const int LBa[5] = {LB0, LB1, LB2, LB3, LB4};

    const float* x = (const float*)d_in[0];
    const int* ei[4];
    for (int l = 0; l < 4; ++l) ei[l] = (const int*)d_in[1 + l];
    const int* down_i[4]; const float* down_w[4];
    const int* up_i[4];   const float* up_w[4];
    for (int i = 0; i < 4; ++i) {
        down_i[i] = (const int*)d_in[6 + 4 * i];
        down_w[i] = (const float*)d_in[7 + 4 * i];
        up_i[i]   = (const int*)d_in[8 + 4 * i];
        up_w[i]   = (const float*)d_in[9 + 4 * i];
    }
    const float* encW[4]; const float* encB[4];
    for (int i = 0; i < 4; ++i) {
        encW[i] = (const float*)d_in[22 + 2 * i];
        encB[i] = (const float*)d_in[23 + 2 * i];
    }
    const float* decW[5];
    for (int i = 0; i < 5; ++i) decW[i] = (const float*)d_in[30 + i];
    const float* decB[4];
    for (int i = 0; i < 4; ++i) decB[i] = (const float*)d_in[35 + i];
    const float* enc_w = (const float*)d_in[39];
    const float* enc_b = (const float*)d_in[40];
    const float* dec_w = (const float*)d_in[41];
    const float* dec_b = (const float*)d_in[42];

    // ---- workspace layout (floats) ----
    float* ws = (float*)d_ws;
    size_t off = 0;
    const size_t SLOT = (size_t)B_ * 65536 * 16;  // 16.78 MB
    float* BA = ws + off; off += SLOT;
    float* BB = ws + off; off += SLOT;
    float* BQ = ws + off; off += SLOT;
    int* cntAll = (int*)(ws + off); off += LB4;
    int* curAll = (int*)(ws + off); off += LB4;
    int* partial = (int*)(ws + off); off += LB4;
    int* bsum = (int*)(ws + off); off += 128;
    int* rowptr[4]; int* ccol[4]; float* cwz[4];
    for (int l = 0; l < 4; ++l) {
        int N = NS_[l], E = DEG_ * N;
        rowptr[l] = (int*)(ws + off); off += (size_t)N + 4;
        ccol[l]   = (int*)(ws + off); off += (size_t)E;
        cwz[l]    = ws + off;         off += (size_t)E;
    }
    float* zbuf = ws + off; off += 256;

    // ---- build CSR + norms for levels 0..3 ----
    hipMemsetAsync(cntAll, 0, (size_t)LB4 * sizeof(int), s);
    hipMemsetAsync(curAll, 0, (size_t)LB4 * sizeof(int), s);
    for (int l = 0; l < 4; ++l) {
        int E = DEG_ * NS_[l];
        cnt_kernel<<<cdivu(E, TPB), TPB, 0, s>>>(ei[l], cntAll + LBa[l], E);
    }
    scanA_kernel<<<85, 256, 0, s>>>(cntAll, partial, bsum);
    scanB_kernel<<<1, 128, 0, s>>>(bsum, 85);
    scanC_kernel<<<cdivu(LB4, TPB), TPB, 0, s>>>(partial, bsum,
                                                 rowptr[0], rowptr[1], rowptr[2], rowptr[3]);
    for (int l = 0; l < 4; ++l) {
        int E = DEG_ * NS_[l];
        fill_kernel<<<cdivu(E, TPB), TPB, 0, s>>>(ei[l], ei[l] + E, rowptr[l],
                                                  curAll + LBa[l], cntAll + LBa[l],
                                                  ccol[l], cwz[l], E);
    }

    // ---- encoder ----
    hipMemcpyAsync(BA, x, (size_t)B_ * 65536 * 3 * sizeof(float),
                   hipMemcpyDeviceToDevice, s);
    run_cheb<3, 16>(BA, BA, BQ, BB, encW[0], encB[0], 1,
                    rowptr[0], ccol[0], cwz[0], NS_[0], s);
    pool_kernel<<<cdivu((size_t)B_ * NS_[1] * 16, TPB), TPB, 0, s>>>(
        BB, BA, down_i[0], down_w[0], NS_[0], NS_[1], 16);
    run_cheb<16, 16>(BA, BA, BQ, BB, encW[1], encB[1], 1,
                     rowptr[1], ccol[1], cwz[1], NS_[1], s);
    pool_kernel<<<cdivu((size_t)B_ * NS_[2] * 16, TPB), TPB, 0, s>>>(
        BB, BA, down_i[1], down_w[1], NS_[1], NS_[2], 16);
    run_cheb<16, 16>(BA, BA, BQ, BB, encW[2], encB[2], 1,
                     rowptr[2], ccol[2], cwz[2], NS_[2], s);
    pool_kernel<<<cdivu((size_t)B_ * NS_[3] * 16, TPB), TPB, 0, s>>>(
        BB, BA, down_i[2], down_w[2], NS_[2], NS_[3], 16);
    run_cheb<16, 32>(BA, BA, BQ, BB, encW[3], encB[3], 1,
                     rowptr[3], ccol[3], cwz[3], NS_[3], s);
    pool_kernel<<<cdivu((size_t)B_ * NS_[4] * 32, TPB), TPB, 0, s>>>(
        BB, BA, down_i[3], down_w[3], NS_[3], NS_[4], 32);

    // ---- latent ----
    dense_enc_kernel<<<B_ * 64, 256, 0, s>>>(BA, enc_w, enc_b, zbuf);
    dense_dec_kernel<<<cdivu((size_t)B_ * 8192, TPB), TPB, 0, s>>>(zbuf, dec_w, dec_b, BB);

    // ---- decoder ----
    pool_kernel<<<cdivu((size_t)B_ * NS_[3] * 32, TPB), TPB, 0, s>>>(
        BB, BA, up_i[3], up_w[3], NS_[4], NS_[3], 32);
    run_cheb<32, 16>(BA, BA, BQ, BB, decW[0], decB[0], 1,
                     rowptr[3], ccol[3], cwz[3], NS_[3], s);
    pool_kernel<<<cdivu((size_t)B_ * NS_[2] * 16, TPB), TPB, 0, s>>>(
        BB, BA, up_i[2], up_w[2], NS_[3], NS_[2], 16);
    run_cheb<16, 16>(BA, BA, BQ, BB, decW[1], decB[1], 1,
                     rowptr[2], ccol[2], cwz[2], NS_[2], s);
    pool_kernel<<<cdivu((size_t)B_ * NS_[1] * 16, TPB), TPB, 0, s>>>(
        BB, BA, up_i[1], up_w[1], NS_[2], NS_[1], 16);
    run_cheb<16, 16>(BA, BA, BQ, BB, decW[2], decB[2], 1,
                     rowptr[1], ccol[1], cwz[1], NS_[1], s);
    pool_kernel<<<cdivu((size_t)B_ * NS_[0] * 16, TPB), TPB, 0, s>>>(
        BB, BA, up_i[0], up_w[0], NS_[1], NS_[0], 16);
    run_cheb<16, 16>(BA, BA, BQ, BB, decW[3], decB[3], 1,
                     rowptr[0], ccol[0], cwz[0], NS_[0], s);
    run_cheb<16, 3>(BB, BB, BQ, (float*)d_out, decW[4], nullptr, 0,
                    rowptr[0], ccol[0], cwz[0], NS_[0], s);
}

// Round 6
// 1593.260 us; speedup vs baseline: 1.6062x; 1.6062x over previous
//
#include <hip/hip_runtime.h>

#define TPB 256

static constexpr int B_ = 4;
static constexpr int DEG_ = 16;

using u16 = unsigned short;

// level bases into the packed count array (sum = 87040 = 85 * 1024)
static constexpr int LB0 = 0, LB1 = 65536, LB2 = 81920, LB3 = 86016, LB4 = 87040;
// cumulative edge counts
static constexpr int CE0 = 0, CE1 = 1048576, CE2 = 1310720, CE3 = 1376256, CE4 = 1392640;

// ---------------- bf16 helpers ----------------

__device__ inline float b2f(u16 u) { return __uint_as_float((unsigned)u << 16); }
__device__ inline u16 f2b(float f) {
    unsigned b = __float_as_uint(f);
    b += 0x7fffu + ((b >> 16) & 1u);   // round-to-nearest-even
    return (u16)(b >> 16);
}

template<int F>
__device__ inline void load_row_bf16(const u16* __restrict__ p, float* v) {
    if constexpr (F % 8 == 0) {
        #pragma unroll
        for (int i = 0; i < F / 8; ++i) {
            uint4 raw = reinterpret_cast<const uint4*>(p)[i];
            unsigned rr[4] = {raw.x, raw.y, raw.z, raw.w};
            #pragma unroll
            for (int k = 0; k < 4; ++k) {
                v[i * 8 + 2 * k]     = __uint_as_float(rr[k] << 16);
                v[i * 8 + 2 * k + 1] = __uint_as_float(rr[k] & 0xffff0000u);
            }
        }
    } else {
        #pragma unroll
        for (int f = 0; f < F; ++f) v[f] = b2f(p[f]);
    }
}

template<int F>
__device__ inline void store_row_bf16(u16* __restrict__ p, const float* v) {
    if constexpr (F % 8 == 0) {
        #pragma unroll
        for (int i = 0; i < F / 8; ++i) {
            uint4 raw;
            unsigned* rr = &raw.x;
            #pragma unroll
            for (int k = 0; k < 4; ++k)
                rr[k] = (unsigned)f2b(v[i * 8 + 2 * k]) |
                        ((unsigned)f2b(v[i * 8 + 2 * k + 1]) << 16);
            reinterpret_cast<uint4*>(p)[i] = raw;
        }
    } else {
        #pragma unroll
        for (int f = 0; f < F; ++f) p[f] = f2b(v[f]);
    }
}

// ---------------- CSR build kernels ----------------

__global__ void cnt_kernel(const int* __restrict__ row, int* __restrict__ cnt, int E) {
    int e = blockIdx.x * blockDim.x + threadIdx.x;
    if (e < E) atomicAdd(&cnt[row[e]], 1);
}

__global__ void scanA_kernel(const int* __restrict__ cnt, int* __restrict__ partial,
                             int* __restrict__ bsum) {
    __shared__ int sdata[256];
    int tid = threadIdx.x;
    int base = blockIdx.x * 1024 + tid * 4;
    int v0 = cnt[base], v1 = cnt[base + 1], v2 = cnt[base + 2], v3 = cnt[base + 3];
    int tsum = v0 + v1 + v2 + v3;
    sdata[tid] = tsum;
    __syncthreads();
    for (int ofs = 1; ofs < 256; ofs <<= 1) {
        int x = (tid >= ofs) ? sdata[tid - ofs] : 0;
        __syncthreads();
        sdata[tid] += x;
        __syncthreads();
    }
    int excl = sdata[tid] - tsum;
    partial[base] = excl;         excl += v0;
    partial[base + 1] = excl;     excl += v1;
    partial[base + 2] = excl;     excl += v2;
    partial[base + 3] = excl;
    if (tid == 255) bsum[blockIdx.x] = sdata[255];
}

__global__ void scanB_kernel(int* __restrict__ bsum, int nb) {
    __shared__ int s[128];
    int tid = threadIdx.x;
    int v = tid < nb ? bsum[tid] : 0;
    s[tid] = v;
    __syncthreads();
    for (int ofs = 1; ofs < 128; ofs <<= 1) {
        int x = (tid >= ofs) ? s[tid - ofs] : 0;
        __syncthreads();
        s[tid] += x;
        __syncthreads();
    }
    if (tid < nb) bsum[tid] = s[tid] - v;
}

__global__ void scanC_kernel(const int* __restrict__ partial, const int* __restrict__ bsum,
                             int* __restrict__ rp0, int* __restrict__ rp1,
                             int* __restrict__ rp2, int* __restrict__ rp3) {
    int i = blockIdx.x * blockDim.x + threadIdx.x;
    if (i >= LB4) return;
    int g = partial[i] + bsum[i >> 10];
    if (i < LB1)      rp0[i - LB0] = g - CE0;
    else if (i < LB2) rp1[i - LB1] = g - CE1;
    else if (i < LB3) rp2[i - LB2] = g - CE2;
    else              rp3[i - LB3] = g - CE3;
    if (i == 0) {
        rp0[LB1 - LB0] = CE1 - CE0;
        rp1[LB2 - LB1] = CE2 - CE1;
        rp2[LB3 - LB2] = CE3 - CE2;
        rp3[LB4 - LB3] = CE4 - CE3;
    }
}

__global__ void fill_kernel(const int* __restrict__ row, const int* __restrict__ col,
                            const int* __restrict__ rowptr, int* __restrict__ cur,
                            const int* __restrict__ cnt, int* __restrict__ ccol,
                            float* __restrict__ cw, int E) {
    int e = blockIdx.x * blockDim.x + threadIdx.x;
    if (e >= E) return;
    int r = row[e], c = col[e];
    int pos = rowptr[r] + atomicAdd(&cur[r], 1);
    float dr = cnt[r] > 0 ? rsqrtf((float)cnt[r]) : 0.f;
    float dc = cnt[c] > 0 ? rsqrtf((float)cnt[c]) : 0.f;
    ccol[pos] = c;
    cw[pos] = dr * dc;
}

// ---------------- fp32 -> bf16 convert ----------------

__global__ void f2b_kernel(const float* __restrict__ in, u16* __restrict__ out, int n) {
    int i = blockIdx.x * blockDim.x + threadIdx.x;
    if (i < n) out[i] = f2b(in[i]);
}

// ---------------- fused Chebyshev sweep (bf16 T-buffers, fp32 accumulation) ----------------
// FIRST: sv = x row; tv = L x (alpha 1); out = sv@W0 + tv@W1 (write); store tv -> dst
// else:  sv = T_{k-2} row; tv = 2 L T_{k-1} - sv; out += tv@Wk; store tv -> dst
// LAST:  no store; + bias/relu; write fp32 out, or bf16 mirror instead if given
template<int F, int G, bool FIRST, bool LAST>
__global__ __launch_bounds__(256) void cheb_sweep(
    const u16* __restrict__ gsrc, const u16* __restrict__ selfp, u16* __restrict__ dst,
    const int* __restrict__ rowptr, const int* __restrict__ ccol,
    const float* __restrict__ cw, const float* __restrict__ Wk,
    const float* __restrict__ bias, float* __restrict__ out,
    u16* __restrict__ mirror, int N, int relu)
{
    constexpr int WSZ = (FIRST ? 2 : 1) * F * G;
    __shared__ float sW[WSZ];
    for (int i = threadIdx.x; i < WSZ; i += 256) sW[i] = Wk[i];
    __syncthreads();
    int t = blockIdx.x * 256 + (int)threadIdx.x;
    if (t >= B_ * N) return;
    int b = t / N;
    int r = t - b * N;
    const float alpha = FIRST ? 1.0f : 2.0f;

    float sv[F];
    load_row_bf16<F>(selfp + (size_t)t * F, sv);
    float tv[F];
    #pragma unroll
    for (int f = 0; f < F; ++f) tv[f] = FIRST ? 0.f : -sv[f];

    const u16* base = gsrc + (size_t)b * N * F;
    int beg = rowptr[r], end = rowptr[r + 1];
    for (int j = beg; j < end; ++j) {
        int c = ccol[j];
        float w = alpha * cw[j];
        float gv[F];
        load_row_bf16<F>(base + (size_t)c * F, gv);
        #pragma unroll
        for (int f = 0; f < F; ++f) tv[f] += w * gv[f];
    }
    if (!LAST) store_row_bf16<F>(dst + (size_t)t * F, tv);

    float acc[G];
    float* orow = out + (size_t)t * G;
    if (FIRST) {
        #pragma unroll
        for (int g = 0; g < G; ++g) acc[g] = 0.f;
        #pragma unroll
        for (int f = 0; f < F; ++f) {
            float xv = sv[f];
            #pragma unroll
            for (int g = 0; g < G; ++g) acc[g] += xv * sW[f * G + g];
        }
        #pragma unroll
        for (int f = 0; f < F; ++f) {
            float tvf = tv[f];
            #pragma unroll
            for (int g = 0; g < G; ++g) acc[g] += tvf * sW[F * G + f * G + g];
        }
    } else {
        #pragma unroll
        for (int g = 0; g < G; ++g) acc[g] = orow[g];
        #pragma unroll
        for (int f = 0; f < F; ++f) {
            float tvf = tv[f];
            #pragma unroll
            for (int g = 0; g < G; ++g) acc[g] += tvf * sW[f * G + g];
        }
    }
    if (LAST) {
        if (bias) {
            #pragma unroll
            for (int g = 0; g < G; ++g) acc[g] += bias[g];
        }
        if (relu) {
            #pragma unroll
            for (int g = 0; g < G; ++g) acc[g] = fmaxf(acc[g], 0.f);
        }
        if (mirror) {
            store_row_bf16<G>(mirror + (size_t)t * G, acc);
            return;  // fp32 out is dead when mirrored
        }
    }
    #pragma unroll
    for (int g = 0; g < G; ++g) orow[g] = acc[g];
}

// ---------------- pool / dense ----------------

// reads fp32, writes bf16 (pool output always feeds a bf16 consumer)
__global__ void pool_kernel(const float* __restrict__ in, u16* __restrict__ out,
                            const int* __restrict__ idx, const float* __restrict__ w,
                            int Nin, int Nout, int F) {
    int t = blockIdx.x * blockDim.x + threadIdx.x;
    if (t >= B_ * Nout * F) return;
    int f = t % F;
    int n = (t / F) % Nout;
    int b = t / (F * Nout);
    float acc = 0.f;
    for (int k = 0; k < 3; ++k) {
        int src = idx[n * 3 + k];
        acc += w[n * 3 + k] * in[((size_t)b * Nin + src) * F + f];
    }
    out[((size_t)b * Nout + n) * F + f] = f2b(acc);
}

__global__ void dense_enc_kernel(const u16* __restrict__ h, const float* __restrict__ W,
                                 const float* __restrict__ bias, float* __restrict__ z) {
    int b = blockIdx.x >> 6;
    int g = blockIdx.x & 63;
    int tid = threadIdx.x;
    float acc = 0.f;
    for (int i = tid; i < 8192; i += 256) acc += b2f(h[b * 8192 + i]) * W[(size_t)i * 64 + g];
    __shared__ float red[256];
    red[tid] = acc;
    __syncthreads();
    for (int sft = 128; sft > 0; sft >>= 1) {
        if (tid < sft) red[tid] += red[tid + sft];
        __syncthreads();
    }
    if (tid == 0) z[b * 64 + g] = fmaxf(red[0] + bias[g], 0.f);
}

__global__ void dense_dec_kernel(const float* __restrict__ z, const float* __restrict__ W,
                                 const float* __restrict__ bias, float* __restrict__ out) {
    int t = blockIdx.x * blockDim.x + threadIdx.x;
    if (t >= B_ * 8192) return;
    int b = t / 8192, j = t % 8192;
    float acc = bias[j];
    for (int k = 0; k < 64; ++k) acc += z[b * 64 + k] * W[(size_t)k * 8192 + j];
    out[t] = fmaxf(acc, 0.f);
}

// ---------------- host ----------------

static inline unsigned cdivu(size_t a, size_t b) { return (unsigned)((a + b - 1) / b); }

template<int F, int G>
static void run_cheb(const u16* X, u16* TP, u16* TQ, float* out,
                     const float* Wk, const float* bias, int relu, u16* mirror,
                     const int* rp, const int* cc, const float* cwp, int N, hipStream_t s) {
    const size_t FG = (size_t)F * G;
    unsigned g = cdivu((size_t)B_ * N, 256);
    // S1: T1 = L x -> TP;  out = x@W0 + T1@W1
    cheb_sweep<F, G, true, false><<<g, 256, 0, s>>>(X, X, TP, rp, cc, cwp,
                                                    Wk, nullptr, out, nullptr, N, 0);
    // S2: T2 = 2 L T1 - x -> TQ
    cheb_sweep<F, G, false, false><<<g, 256, 0, s>>>(TP, X, TQ, rp, cc, cwp,
                                                     Wk + 2 * FG, nullptr, out, nullptr, N, 0);
    // S3: T3 = 2 L T2 - T1 -> TP (in place over T1)
    cheb_sweep<F, G, false, false><<<g, 256, 0, s>>>(TQ, TP, TP, rp, cc, cwp,
                                                     Wk + 3 * FG, nullptr, out, nullptr, N, 0);
    // S4: T4 = 2 L T3 - T2 -> TQ
    cheb_sweep<F, G, false, false><<<g, 256, 0, s>>>(TP, TQ, TQ, rp, cc, cwp,
                                                     Wk + 4 * FG, nullptr, out, nullptr, N, 0);
    // S5: T5 = 2 L T4 - T3; out += T5@W5 (+bias/relu); no store
    cheb_sweep<F, G, false, true><<<g, 256, 0, s>>>(TQ, TP, nullptr, rp, cc, cwp,
                                                    Wk + 5 * FG, bias, out, mirror, N, relu);
}

extern "C" void kernel_launch(void* const* d_in, const int* in_sizes, int n_in,
                              void* d_out, int out_size, void* d_ws, size_t ws_size,
                              hipStream_t stream) {
    (void)in_sizes; (void)n_in; (void)out_size; (void)ws_size;
    hipStream_t s = stream;

    static const int NS_[5] = {65536, 16384, 4096, 1024, 256};
    static const int LBa[5] = {LB0, LB1, LB2, LB3, LB4};

    const float* x = (const float*)d_in[0];
    const int* ei[4];
    for (int l = 0; l < 4; ++l) ei[l] = (const int*)d_in[1 + l];
    const int* down_i[4]; const float* down_w[4];
    const int* up_i[4];   const float* up_w[4];
    for (int i = 0; i < 4; ++i) {
        down_i[i] = (const int*)d_in[6 + 4 * i];
        down_w[i] = (const float*)d_in[7 + 4 * i];
        up_i[i]   = (const int*)d_in[8 + 4 * i];
        up_w[i]   = (const float*)d_in[9 + 4 * i];
    }
    const float* encW[4]; const float* encB[4];
    for (int i = 0; i < 4; ++i) {
        encW[i] = (const float*)d_in[22 + 2 * i];
        encB[i] = (const float*)d_in[23 + 2 * i];
    }
    const float* decW[5];
    for (int i = 0; i < 5; ++i) decW[i] = (const float*)d_in[30 + i];
    const float* decB[4];
    for (int i = 0; i < 4; ++i) decB[i] = (const float*)d_in[35 + i];
    const float* enc_w = (const float*)d_in[39];
    const float* enc_b = (const float*)d_in[40];
    const float* dec_w = (const float*)d_in[41];
    const float* dec_b = (const float*)d_in[42];

    // ---- workspace layout ----
    float* ws = (float*)d_ws;
    size_t off = 0;                                   // in floats
    const size_t SLOT = (size_t)B_ * 65536 * 16;      // 4,194,304
    float* BA = ws + off; off += SLOT;                // fp32 conv-out / pool-in
    u16* XB = (u16*)(ws + off); off += SLOT / 2;      // bf16 conv-in
    u16* TP = (u16*)(ws + off); off += SLOT / 2;      // bf16 T ping
    u16* TQ = (u16*)(ws + off); off += SLOT / 2;      // bf16 T pong
    int* cntAll = (int*)(ws + off); off += LB4;
    int* curAll = (int*)(ws + off); off += LB4;
    int* partial = (int*)(ws + off); off += LB4;
    int* bsum = (int*)(ws + off); off += 128;
    int* rowptr[4]; int* ccol[4]; float* cwz[4];
    for (int l = 0; l < 4; ++l) {
        int N = NS_[l], E = DEG_ * N;
        rowptr[l] = (int*)(ws + off); off += (size_t)N + 4;
        ccol[l]   = (int*)(ws + off); off += (size_t)E;
        cwz[l]    = ws + off;         off += (size_t)E;
    }
    float* zbuf = ws + off; off += 256;

    // ---- build CSR + norms for levels 0..3 ----
    hipMemsetAsync(cntAll, 0, (size_t)LB4 * sizeof(int), s);
    hipMemsetAsync(curAll, 0, (size_t)LB4 * sizeof(int), s);
    for (int l = 0; l < 4; ++l) {
        int E = DEG_ * NS_[l];
        cnt_kernel<<<cdivu(E, TPB), TPB, 0, s>>>(ei[l], cntAll + LBa[l], E);
    }
    scanA_kernel<<<85, 256, 0, s>>>(cntAll, partial, bsum);
    scanB_kernel<<<1, 128, 0, s>>>(bsum, 85);
    scanC_kernel<<<cdivu(LB4, TPB), TPB, 0, s>>>(partial, bsum,
                                                 rowptr[0], rowptr[1], rowptr[2], rowptr[3]);
    for (int l = 0; l < 4; ++l) {
        int E = DEG_ * NS_[l];
        fill_kernel<<<cdivu(E, TPB), TPB, 0, s>>>(ei[l], ei[l] + E, rowptr[l],
                                                  curAll + LBa[l], cntAll + LBa[l],
                                                  ccol[l], cwz[l], E);
    }

    // ---- encoder ----
    f2b_kernel<<<cdivu((size_t)B_ * 65536 * 3, TPB), TPB, 0, s>>>(x, XB, B_ * 65536 * 3);
    run_cheb<3, 16>(XB, TP, TQ, BA, encW[0], encB[0], 1, nullptr,
                    rowptr[0], ccol[0], cwz[0], NS_[0], s);
    pool_kernel<<<cdivu((size_t)B_ * NS_[1] * 16, TPB), TPB, 0, s>>>(
        BA, XB, down_i[0], down_w[0], NS_[0], NS_[1], 16);
    run_cheb<16, 16>(XB, TP, TQ, BA, encW[1], encB[1], 1, nullptr,
                     rowptr[1], ccol[1], cwz[1], NS_[1], s);
    pool_kernel<<<cdivu((size_t)B_ * NS_[2] * 16, TPB), TPB, 0, s>>>(
        BA, XB, down_i[1], down_w[1], NS_[1], NS_[2], 16);
    run_cheb<16, 16>(XB, TP, TQ, BA, encW[2], encB[2], 1, nullptr,
                     rowptr[2], ccol[2], cwz[2], NS_[2], s);
    pool_kernel<<<cdivu((size_t)B_ * NS_[3] * 16, TPB), TPB, 0, s>>>(
        BA, XB, down_i[2], down_w[2], NS_[2], NS_[3], 16);
    run_cheb<16, 32>(XB, TP, TQ, BA, encW[3], encB[3], 1, nullptr,
                     rowptr[3], ccol[3], cwz[3], NS_[3], s);
    pool_kernel<<<cdivu((size_t)B_ * NS_[4] * 32, TPB), TPB, 0, s>>>(
        BA, XB, down_i[3], down_w[3], NS_[3], NS_[4], 32);

    // ---- latent ----
    dense_enc_kernel<<<B_ * 64, 256, 0, s>>>(XB, enc_w, enc_b, zbuf);
    dense_dec_kernel<<<cdivu((size_t)B_ * 8192, TPB), TPB, 0, s>>>(zbuf, dec_w, dec_b, BA);

    // ---- decoder ----
    pool_kernel<<<cdivu((size_t)B_ * NS_[3] * 32, TPB), TPB, 0, s>>>(
        BA, XB, up_i[3], up_w[3], NS_[4], NS_[3], 32);
    run_cheb<32, 16>(XB, TP, TQ, BA, decW[0], decB[0], 1, nullptr,
                     rowptr[3], ccol[3], cwz[3], NS_[3], s);
    pool_kernel<<<cdivu((size_t)B_ * NS_[2] * 16, TPB), TPB, 0, s>>>(
        BA, XB, up_i[2], up_w[2], NS_[3], NS_[2], 16);
    run_cheb<16, 16>(XB, TP, TQ, BA, decW[1], decB[1], 1, nullptr,
                     rowptr[2], ccol[2], cwz[2], NS_[2], s);
    pool_kernel<<<cdivu((size_t)B_ * NS_[1] * 16, TPB), TPB, 0, s>>>(
        BA, XB, up_i[1], up_w[1], NS_[2], NS_[1], 16);
    run_cheb<16, 16>(XB, TP, TQ, BA, decW[2], decB[2], 1, nullptr,
                     rowptr[1], ccol[1], cwz[1], NS_[1], s);
    pool_kernel<<<cdivu((size_t)B_ * NS_[0] * 16, TPB), TPB, 0, s>>>(
        BA, XB, up_i[0], up_w[0], NS_[1], NS_[0], 16);
    // dec3: bf16 mirror -> XB (feeds dec4 directly; fp32 out skipped when mirrored)
    run_cheb<16, 16>(XB, TP, TQ, BA, decW[3], decB[3], 1, XB,
                     rowptr[0], ccol[0], cwz[0], NS_[0], s);
    // final conv: 16 -> 3, no bias/relu, fp32 -> d_out
    run_cheb<16, 3>(XB, TP, TQ, (float*)d_out, decW[4], nullptr, 0, nullptr,
                    rowptr[0], ccol[0], cwz[0], NS_[0], s);
}

// Round 7
// 1207.916 us; speedup vs baseline: 2.1186x; 1.3190x over previous
//
#include <hip/hip_runtime.h>

#define TPB 256

static constexpr int B_ = 4;
static constexpr int DEG_ = 16;

using u16 = unsigned short;

// level bases into the packed count array (sum = 87040 = 85 * 1024)
static constexpr int LB0 = 0, LB1 = 65536, LB2 = 81920, LB3 = 86016, LB4 = 87040;
// cumulative edge counts
static constexpr int CE0 = 0, CE1 = 1048576, CE2 = 1310720, CE3 = 1376256, CE4 = 1392640;

// ---------------- bf16 helpers ----------------

__device__ inline float b2f(u16 u) { return __uint_as_float((unsigned)u << 16); }
__device__ inline u16 f2b(float f) {
    unsigned b = __float_as_uint(f);
    b += 0x7fffu + ((b >> 16) & 1u);   // round-to-nearest-even
    return (u16)(b >> 16);
}

template<int F>
__device__ inline void load_row_bf16(const u16* __restrict__ p, float* v) {
    if constexpr (F % 8 == 0) {
        #pragma unroll
        for (int i = 0; i < F / 8; ++i) {
            uint4 raw = reinterpret_cast<const uint4*>(p)[i];
            unsigned rr[4] = {raw.x, raw.y, raw.z, raw.w};
            #pragma unroll
            for (int k = 0; k < 4; ++k) {
                v[i * 8 + 2 * k]     = __uint_as_float(rr[k] << 16);
                v[i * 8 + 2 * k + 1] = __uint_as_float(rr[k] & 0xffff0000u);
            }
        }
    } else {
        #pragma unroll
        for (int f = 0; f < F; ++f) v[f] = b2f(p[f]);
    }
}

template<int F>
__device__ inline void store_row_bf16(u16* __restrict__ p, const float* v) {
    if constexpr (F % 8 == 0) {
        #pragma unroll
        for (int i = 0; i < F / 8; ++i) {
            uint4 raw;
            unsigned* rr = &raw.x;
            #pragma unroll
            for (int k = 0; k < 4; ++k)
                rr[k] = (unsigned)f2b(v[i * 8 + 2 * k]) |
                        ((unsigned)f2b(v[i * 8 + 2 * k + 1]) << 16);
            reinterpret_cast<uint4*>(p)[i] = raw;
        }
    } else {
        #pragma unroll
        for (int f = 0; f < F; ++f) p[f] = f2b(v[f]);
    }
}

// ---------------- CSR build kernels ----------------

__global__ void cnt_kernel(const int* __restrict__ row, int* __restrict__ cnt, int E) {
    int e = blockIdx.x * blockDim.x + threadIdx.x;
    if (e < E) atomicAdd(&cnt[row[e]], 1);
}

__global__ void scanA_kernel(const int* __restrict__ cnt, int* __restrict__ partial,
                             int* __restrict__ bsum) {
    __shared__ int sdata[256];
    int tid = threadIdx.x;
    int base = blockIdx.x * 1024 + tid * 4;
    int v0 = cnt[base], v1 = cnt[base + 1], v2 = cnt[base + 2], v3 = cnt[base + 3];
    int tsum = v0 + v1 + v2 + v3;
    sdata[tid] = tsum;
    __syncthreads();
    for (int ofs = 1; ofs < 256; ofs <<= 1) {
        int x = (tid >= ofs) ? sdata[tid - ofs] : 0;
        __syncthreads();
        sdata[tid] += x;
        __syncthreads();
    }
    int excl = sdata[tid] - tsum;
    partial[base] = excl;         excl += v0;
    partial[base + 1] = excl;     excl += v1;
    partial[base + 2] = excl;     excl += v2;
    partial[base + 3] = excl;
    if (tid == 255) bsum[blockIdx.x] = sdata[255];
}

__global__ void scanB_kernel(int* __restrict__ bsum, int nb) {
    __shared__ int s[128];
    int tid = threadIdx.x;
    int v = tid < nb ? bsum[tid] : 0;
    s[tid] = v;
    __syncthreads();
    for (int ofs = 1; ofs < 128; ofs <<= 1) {
        int x = (tid >= ofs) ? s[tid - ofs] : 0;
        __syncthreads();
        s[tid] += x;
        __syncthreads();
    }
    if (tid < nb) bsum[tid] = s[tid] - v;
}

__global__ void scanC_kernel(const int* __restrict__ partial, const int* __restrict__ bsum,
                             int* __restrict__ rp0, int* __restrict__ rp1,
                             int* __restrict__ rp2, int* __restrict__ rp3) {
    int i = blockIdx.x * blockDim.x + threadIdx.x;
    if (i >= LB4) return;
    int g = partial[i] + bsum[i >> 10];
    if (i < LB1)      rp0[i - LB0] = g - CE0;
    else if (i < LB2) rp1[i - LB1] = g - CE1;
    else if (i < LB3) rp2[i - LB2] = g - CE2;
    else              rp3[i - LB3] = g - CE3;
    if (i == 0) {
        rp0[LB1 - LB0] = CE1 - CE0;
        rp1[LB2 - LB1] = CE2 - CE1;
        rp2[LB3 - LB2] = CE3 - CE2;
        rp3[LB4 - LB3] = CE4 - CE3;
    }
}

__global__ void fill_kernel(const int* __restrict__ row, const int* __restrict__ col,
                            const int* __restrict__ rowptr, int* __restrict__ cur,
                            const int* __restrict__ cnt, int* __restrict__ ccol,
                            float* __restrict__ cw, int E) {
    int e = blockIdx.x * blockDim.x + threadIdx.x;
    if (e >= E) return;
    int r = row[e], c = col[e];
    int pos = rowptr[r] + atomicAdd(&cur[r], 1);
    float dr = cnt[r] > 0 ? rsqrtf((float)cnt[r]) : 0.f;
    float dc = cnt[c] > 0 ? rsqrtf((float)cnt[c]) : 0.f;
    ccol[pos] = c;
    cw[pos] = dr * dc;
}

// ---------------- fp32 [B][N][3] -> bf16 [N][B][3] transpose-convert ----------------

__global__ void f2b_tr_kernel(const float* __restrict__ in, u16* __restrict__ out, int N) {
    int t = blockIdx.x * blockDim.x + threadIdx.x;   // output-ordered
    if (t >= B_ * N * 3) return;
    int f = t % 3;
    int nb = t / 3;
    int b = nb & 3;
    int n = nb >> 2;
    out[t] = f2b(in[((size_t)b * N + n) * 3 + f]);
}

// ---------------- fused Chebyshev sweep ----------------
// Batch-interleaved layout: feature buffers are [N][B][F]; thread t -> (r=t>>2, b=t&3),
// so row index (r*4+b) == t. Gather for neighbor c reads (c*4+b)*F: the 4 lanes of a
// node-group fetch contiguous 4*F*2 bytes -> fully used cache lines.
// FIRST: sv = x row; tv = L x (alpha 1); out = sv@W0 + tv@W1 (write); store tv -> dst
// else:  sv = T_{k-2} row; tv = 2 L T_{k-1} - sv; out += tv@Wk; store tv -> dst
// LAST:  no store; + bias/relu; write fp32 out (interleaved, or [B][N][G] if OSTD),
//        or bf16 mirror instead if given
template<int F, int G, bool FIRST, bool LAST, bool OSTD>
__global__ __launch_bounds__(256) void cheb_sweep(
    const u16* __restrict__ gsrc, const u16* __restrict__ selfp, u16* __restrict__ dst,
    const int* __restrict__ rowptr, const int* __restrict__ ccol,
    const float* __restrict__ cw, const float* __restrict__ Wk,
    const float* __restrict__ bias, float* __restrict__ out,
    u16* __restrict__ mirror, int N, int relu)
{
    constexpr int WSZ = (FIRST ? 2 : 1) * F * G;
    __shared__ float sW[WSZ];
    for (int i = threadIdx.x; i < WSZ; i += 256) sW[i] = Wk[i];
    __syncthreads();
    int t = blockIdx.x * 256 + (int)threadIdx.x;
    if (t >= B_ * N) return;
    int r = t >> 2;
    int b = t & 3;
    const float alpha = FIRST ? 1.0f : 2.0f;

    float sv[F];
    load_row_bf16<F>(selfp + (size_t)t * F, sv);
    float tv[F];
    #pragma unroll
    for (int f = 0; f < F; ++f) tv[f] = FIRST ? 0.f : -sv[f];

    int beg = rowptr[r], end = rowptr[r + 1];
    for (int j = beg; j < end; ++j) {
        int c = ccol[j];
        float w = alpha * cw[j];
        float gv[F];
        load_row_bf16<F>(gsrc + (size_t)((c << 2) | b) * F, gv);
        #pragma unroll
        for (int f = 0; f < F; ++f) tv[f] += w * gv[f];
    }
    if (!LAST) store_row_bf16<F>(dst + (size_t)t * F, tv);

    float acc[G];
    float* orow = OSTD ? out + ((size_t)b * N + r) * G : out + (size_t)t * G;
    if (FIRST) {
        #pragma unroll
        for (int g = 0; g < G; ++g) acc[g] = 0.f;
        #pragma unroll
        for (int f = 0; f < F; ++f) {
            float xv = sv[f];
            #pragma unroll
            for (int g = 0; g < G; ++g) acc[g] += xv * sW[f * G + g];
        }
        #pragma unroll
        for (int f = 0; f < F; ++f) {
            float tvf = tv[f];
            #pragma unroll
            for (int g = 0; g < G; ++g) acc[g] += tvf * sW[F * G + f * G + g];
        }
    } else {
        #pragma unroll
        for (int g = 0; g < G; ++g) acc[g] = orow[g];
        #pragma unroll
        for (int f = 0; f < F; ++f) {
            float tvf = tv[f];
            #pragma unroll
            for (int g = 0; g < G; ++g) acc[g] += tvf * sW[f * G + g];
        }
    }
    if (LAST) {
        if (bias) {
            #pragma unroll
            for (int g = 0; g < G; ++g) acc[g] += bias[g];
        }
        if (relu) {
            #pragma unroll
            for (int g = 0; g < G; ++g) acc[g] = fmaxf(acc[g], 0.f);
        }
        if (mirror) {
            store_row_bf16<G>(mirror + (size_t)t * G, acc);
            return;  // fp32 out is dead when mirrored
        }
    }
    #pragma unroll
    for (int g = 0; g < G; ++g) orow[g] = acc[g];
}

// ---------------- pool / dense (all interleaved [N][B][F]) ----------------

// in fp32 [Nin][B][F], out bf16 [Nout][B][F]
__global__ void pool_kernel(const float* __restrict__ in, u16* __restrict__ out,
                            const int* __restrict__ idx, const float* __restrict__ w,
                            int Nin, int Nout, int F) {
    int t = blockIdx.x * blockDim.x + threadIdx.x;
    if (t >= B_ * Nout * F) return;
    int f = t % F;
    int nb = t / F;
    int b = nb & 3;
    int n = nb >> 2;
    float acc = 0.f;
    for (int k = 0; k < 3; ++k) {
        int src = idx[n * 3 + k];
        acc += w[n * 3 + k] * in[(size_t)((src << 2) | b) * F + f];
    }
    out[t] = f2b(acc);
}

// h bf16 interleaved [256][4][32]; logical h[b, i], i = n*32+f
__global__ void dense_enc_kernel(const u16* __restrict__ h, const float* __restrict__ W,
                                 const float* __restrict__ bias, float* __restrict__ z) {
    int b = blockIdx.x >> 6;
    int g = blockIdx.x & 63;
    int tid = threadIdx.x;
    float acc = 0.f;
    for (int i = tid; i < 8192; i += 256) {
        int n = i >> 5, f = i & 31;
        acc += b2f(h[(((size_t)n << 2) | b) * 32 + f]) * W[(size_t)i * 64 + g];
    }
    __shared__ float red[256];
    red[tid] = acc;
    __syncthreads();
    for (int sft = 128; sft > 0; sft >>= 1) {
        if (tid < sft) red[tid] += red[tid + sft];
        __syncthreads();
    }
    if (tid == 0) z[b * 64 + g] = fmaxf(red[0] + bias[g], 0.f);
}

// out fp32 interleaved [256][4][32]; logical out[b, j], j = n*32+f
__global__ void dense_dec_kernel(const float* __restrict__ z, const float* __restrict__ W,
                                 const float* __restrict__ bias, float* __restrict__ out) {
    int t = blockIdx.x * blockDim.x + threadIdx.x;
    if (t >= B_ * 8192) return;
    int b = t / 8192, j = t % 8192;
    float acc = bias[j];
    for (int k = 0; k < 64; ++k) acc += z[b * 64 + k] * W[(size_t)k * 8192 + j];
    int n = j >> 5, f = j & 31;
    out[(((size_t)n << 2) | b) * 32 + f] = fmaxf(acc, 0.f);
}

// ---------------- host ----------------

static inline unsigned cdivu(size_t a, size_t b) { return (unsigned)((a + b - 1) / b); }

template<int F, int G, bool OSTD = false>
static void run_cheb(const u16* X, u16* TP, u16* TQ, float* out,
                     const float* Wk, const float* bias, int relu, u16* mirror,
                     const int* rp, const int* cc, const float* cwp, int N, hipStream_t s) {
    const size_t FG = (size_t)F * G;
    unsigned g = cdivu((size_t)B_ * N, 256);
    // S1: T1 = L x -> TP;  out = x@W0 + T1@W1
    cheb_sweep<F, G, true, false, OSTD><<<g, 256, 0, s>>>(X, X, TP, rp, cc, cwp,
                                                    Wk, nullptr, out, nullptr, N, 0);
    // S2: T2 = 2 L T1 - x -> TQ
    cheb_sweep<F, G, false, false, OSTD><<<g, 256, 0, s>>>(TP, X, TQ, rp, cc, cwp,
                                                     Wk + 2 * FG, nullptr, out, nullptr, N, 0);
    // S3: T3 = 2 L T2 - T1 -> TP (in place over T1)
    cheb_sweep<F, G, false, false, OSTD><<<g, 256, 0, s>>>(TQ, TP, TP, rp, cc, cwp,
                                                     Wk + 3 * FG, nullptr, out, nullptr, N, 0);
    // S4: T4 = 2 L T3 - T2 -> TQ
    cheb_sweep<F, G, false, false, OSTD><<<g, 256, 0, s>>>(TP, TQ, TQ, rp, cc, cwp,
                                                     Wk + 4 * FG, nullptr, out, nullptr, N, 0);
    // S5: T5 = 2 L T4 - T3; out += T5@W5 (+bias/relu); no store
    cheb_sweep<F, G, false, true, OSTD><<<g, 256, 0, s>>>(TQ, TP, nullptr, rp, cc, cwp,
                                                    Wk + 5 * FG, bias, out, mirror, N, relu);
}

extern "C" void kernel_launch(void* const* d_in, const int* in_sizes, int n_in,
                              void* d_out, int out_size, void* d_ws, size_t ws_size,
                              hipStream_t stream) {
    (void)in_sizes; (void)n_in; (void)out_size; (void)ws_size;
    hipStream_t s = stream;

    static const int NS_[5] = {65536, 16384, 4096, 1024, 256};
    static const int LBa[5] = {LB0, LB1, LB2, LB3, LB4};

    const float* x = (const float*)d_in[0];
    const int* ei[4];
    for (int l = 0; l < 4; ++l) ei[l] = (const int*)d_in[1 + l];
    const int* down_i[4]; const float* down_w[4];
    const int* up_i[4];   const float* up_w[4];
    for (int i = 0; i < 4; ++i) {
        down_i[i] = (const int*)d_in[6 + 4 * i];
        down_w[i] = (const float*)d_in[7 + 4 * i];
        up_i[i]   = (const int*)d_in[8 + 4 * i];
        up_w[i]   = (const float*)d_in[9 + 4 * i];
    }
    const float* encW[4]; const float* encB[4];
    for (int i = 0; i < 4; ++i) {
        encW[i] = (const float*)d_in[22 + 2 * i];
        encB[i] = (const float*)d_in[23 + 2 * i];
    }
    const float* decW[5];
    for (int i = 0; i < 5; ++i) decW[i] = (const float*)d_in[30 + i];
    const float* decB[4];
    for (int i = 0; i < 4; ++i) decB[i] = (const float*)d_in[35 + i];
    const float* enc_w = (const float*)d_in[39];
    const float* enc_b = (const float*)d_in[40];
    const float* dec_w = (const float*)d_in[41];
    const float* dec_b = (const float*)d_in[42];

    // ---- workspace layout ----
    float* ws = (float*)d_ws;
    size_t off = 0;                                   // in floats
    const size_t SLOT = (size_t)B_ * 65536 * 16;      // 4,194,304
    float* BA = ws + off; off += SLOT;                // fp32 conv-out / pool-in (interleaved)
    u16* XB = (u16*)(ws + off); off += SLOT / 2;      // bf16 conv-in (interleaved)
    u16* TP = (u16*)(ws + off); off += SLOT / 2;      // bf16 T ping
    u16* TQ = (u16*)(ws + off); off += SLOT / 2;      // bf16 T pong
    int* cntAll = (int*)(ws + off); off += LB4;
    int* curAll = (int*)(ws + off); off += LB4;
    int* partial = (int*)(ws + off); off += LB4;
    int* bsum = (int*)(ws + off); off += 128;
    int* rowptr[4]; int* ccol[4]; float* cwz[4];
    for (int l = 0; l < 4; ++l) {
        int N = NS_[l], E = DEG_ * N;
        rowptr[l] = (int*)(ws + off); off += (size_t)N + 4;
        ccol[l]   = (int*)(ws + off); off += (size_t)E;
        cwz[l]    = ws + off;         off += (size_t)E;
    }
    float* zbuf = ws + off; off += 256;

    // ---- build CSR + norms for levels 0..3 ----
    hipMemsetAsync(cntAll, 0, (size_t)LB4 * sizeof(int), s);
    hipMemsetAsync(curAll, 0, (size_t)LB4 * sizeof(int), s);
    for (int l = 0; l < 4; ++l) {
        int E = DEG_ * NS_[l];
        cnt_kernel<<<cdivu(E, TPB), TPB, 0, s>>>(ei[l], cntAll + LBa[l], E);
    }
    scanA_kernel<<<85, 256, 0, s>>>(cntAll, partial, bsum);
    scanB_kernel<<<1, 128, 0, s>>>(bsum, 85);
    scanC_kernel<<<cdivu(LB4, TPB), TPB, 0, s>>>(partial, bsum,
                                                 rowptr[0], rowptr[1], rowptr[2], rowptr[3]);
    for (int l = 0; l < 4; ++l) {
        int E = DEG_ * NS_[l];
        fill_kernel<<<cdivu(E, TPB), TPB, 0, s>>>(ei[l], ei[l] + E, rowptr[l],
                                                  curAll + LBa[l], cntAll + LBa[l],
                                                  ccol[l], cwz[l], E);
    }

    // ---- encoder ----
    f2b_tr_kernel<<<cdivu((size_t)B_ * 65536 * 3, TPB), TPB, 0, s>>>(x, XB, 65536);
    run_cheb<3, 16>(XB, TP, TQ, BA, encW[0], encB[0], 1, nullptr,
                    rowptr[0], ccol[0], cwz[0], NS_[0], s);
    pool_kernel<<<cdivu((size_t)B_ * NS_[1] * 16, TPB), TPB, 0, s>>>(
        BA, XB, down_i[0], down_w[0], NS_[0], NS_[1], 16);
    run_cheb<16, 16>(XB, TP, TQ, BA, encW[1], encB[1], 1, nullptr,
                     rowptr[1], ccol[1], cwz[1], NS_[1], s);
    pool_kernel<<<cdivu((size_t)B_ * NS_[2] * 16, TPB), TPB, 0, s>>>(
        BA, XB, down_i[1], down_w[1], NS_[1], NS_[2], 16);
    run_cheb<16, 16>(XB, TP, TQ, BA, encW[2], encB[2], 1, nullptr,
                     rowptr[2], ccol[2], cwz[2], NS_[2], s);
    pool_kernel<<<cdivu((size_t)B_ * NS_[3] * 16, TPB), TPB, 0, s>>>(
        BA, XB, down_i[2], down_w[2], NS_[2], NS_[3], 16);
    run_cheb<16, 32>(XB, TP, TQ, BA, encW[3], encB[3], 1, nullptr,
                     rowptr[3], ccol[3], cwz[3], NS_[3], s);
    pool_kernel<<<cdivu((size_t)B_ * NS_[4] * 32, TPB), TPB, 0, s>>>(
        BA, XB, down_i[3], down_w[3], NS_[3], NS_[4], 32);

    // ---- latent ----
    dense_enc_kernel<<<B_ * 64, 256, 0, s>>>(XB, enc_w, enc_b, zbuf);
    dense_dec_kernel<<<cdivu((size_t)B_ * 8192, TPB), TPB, 0, s>>>(zbuf, dec_w, dec_b, BA);

    // ---- decoder ----
    pool_kernel<<<cdivu((size_t)B_ * NS_[3] * 32, TPB), TPB, 0, s>>>(
        BA, XB, up_i[3], up_w[3], NS_[4], NS_[3], 32);
    run_cheb<32, 16>(XB, TP, TQ, BA, decW[0], decB[0], 1, nullptr,
                     rowptr[3], ccol[3], cwz[3], NS_[3], s);
    pool_kernel<<<cdivu((size_t)B_ * NS_[2] * 16, TPB), TPB, 0, s>>>(
        BA, XB, up_i[2], up_w[2], NS_[3], NS_[2], 16);
    run_cheb<16, 16>(XB, TP, TQ, BA, decW[1], decB[1], 1, nullptr,
                     rowptr[2], ccol[2], cwz[2], NS_[2], s);
    pool_kernel<<<cdivu((size_t)B_ * NS_[1] * 16, TPB), TPB, 0, s>>>(
        BA, XB, up_i[1], up_w[1], NS_[2], NS_[1], 16);
    run_cheb<16, 16>(XB, TP, TQ, BA, decW[2], decB[2], 1, nullptr,
                     rowptr[1], ccol[1], cwz[1], NS_[1], s);
    pool_kernel<<<cdivu((size_t)B_ * NS_[0] * 16, TPB), TPB, 0, s>>>(
        BA, XB, up_i[0], up_w[0], NS_[1], NS_[0], 16);
    // dec3: bf16 mirror -> XB (feeds dec4 directly; fp32 out skipped when mirrored)
    run_cheb<16, 16>(XB, TP, TQ, BA, decW[3], decB[3], 1, XB,
                     rowptr[0], ccol[0], cwz[0], NS_[0], s);
    // final conv: 16 -> 3, no bias/relu, fp32 -> d_out in canonical [B][N][3]
    run_cheb<16, 3, true>(XB, TP, TQ, (float*)d_out, decW[4], nullptr, 0, nullptr,
                          rowptr[0], ccol[0], cwz[0], NS_[0], s);
}

// Round 8
// 1135.994 us; speedup vs baseline: 2.2528x; 1.0633x over previous
//
#include <hip/hip_runtime.h>

#define TPB 256

static constexpr int B_ = 4;
static constexpr int DEG_ = 16;

using u16 = unsigned short;

// level bases into the packed count array (sum = 87040 = 85 * 1024)
static constexpr int LB0 = 0, LB1 = 65536, LB2 = 81920, LB3 = 86016, LB4 = 87040;
// cumulative edge counts
static constexpr int CE0 = 0, CE1 = 1048576, CE2 = 1310720, CE3 = 1376256, CE4 = 1392640;

// ---------------- bf16 helpers ----------------

__device__ inline float b2f(u16 u) { return __uint_as_float((unsigned)u << 16); }
__device__ inline u16 f2b(float f) {
    unsigned b = __float_as_uint(f);
    b += 0x7fffu + ((b >> 16) & 1u);   // round-to-nearest-even
    return (u16)(b >> 16);
}

template<int F>
__device__ inline void load_row_bf16(const u16* __restrict__ p, float* v) {
    if constexpr (F % 8 == 0) {
        #pragma unroll
        for (int i = 0; i < F / 8; ++i) {
            uint4 raw = reinterpret_cast<const uint4*>(p)[i];
            unsigned rr[4] = {raw.x, raw.y, raw.z, raw.w};
            #pragma unroll
            for (int k = 0; k < 4; ++k) {
                v[i * 8 + 2 * k]     = __uint_as_float(rr[k] << 16);
                v[i * 8 + 2 * k + 1] = __uint_as_float(rr[k] & 0xffff0000u);
            }
        }
    } else {
        #pragma unroll
        for (int f = 0; f < F; ++f) v[f] = b2f(p[f]);
    }
}

template<int F>
__device__ inline void store_row_bf16(u16* __restrict__ p, const float* v) {
    if constexpr (F % 8 == 0) {
        #pragma unroll
        for (int i = 0; i < F / 8; ++i) {
            uint4 raw;
            unsigned* rr = &raw.x;
            #pragma unroll
            for (int k = 0; k < 4; ++k)
                rr[k] = (unsigned)f2b(v[i * 8 + 2 * k]) |
                        ((unsigned)f2b(v[i * 8 + 2 * k + 1]) << 16);
            reinterpret_cast<uint4*>(p)[i] = raw;
        }
    } else {
        #pragma unroll
        for (int f = 0; f < F; ++f) p[f] = f2b(v[f]);
    }
}

// ---------------- CSR build kernels ----------------

__global__ void cnt_kernel(const int* __restrict__ row, int* __restrict__ cnt, int E) {
    int e = blockIdx.x * blockDim.x + threadIdx.x;
    if (e < E) atomicAdd(&cnt[row[e]], 1);
}

__global__ void dis_kernel(const int* __restrict__ cnt, float* __restrict__ dis, int n) {
    int i = blockIdx.x * blockDim.x + threadIdx.x;
    if (i < n) dis[i] = cnt[i] > 0 ? rsqrtf((float)cnt[i]) : 0.f;
}

__global__ void scanA_kernel(const int* __restrict__ cnt, int* __restrict__ partial,
                             int* __restrict__ bsum) {
    __shared__ int sdata[256];
    int tid = threadIdx.x;
    int base = blockIdx.x * 1024 + tid * 4;
    int v0 = cnt[base], v1 = cnt[base + 1], v2 = cnt[base + 2], v3 = cnt[base + 3];
    int tsum = v0 + v1 + v2 + v3;
    sdata[tid] = tsum;
    __syncthreads();
    for (int ofs = 1; ofs < 256; ofs <<= 1) {
        int x = (tid >= ofs) ? sdata[tid - ofs] : 0;
        __syncthreads();
        sdata[tid] += x;
        __syncthreads();
    }
    int excl = sdata[tid] - tsum;
    partial[base] = excl;         excl += v0;
    partial[base + 1] = excl;     excl += v1;
    partial[base + 2] = excl;     excl += v2;
    partial[base + 3] = excl;
    if (tid == 255) bsum[blockIdx.x] = sdata[255];
}

__global__ void scanB_kernel(int* __restrict__ bsum, int nb) {
    __shared__ int s[128];
    int tid = threadIdx.x;
    int v = tid < nb ? bsum[tid] : 0;
    s[tid] = v;
    __syncthreads();
    for (int ofs = 1; ofs < 128; ofs <<= 1) {
        int x = (tid >= ofs) ? s[tid - ofs] : 0;
        __syncthreads();
        s[tid] += x;
        __syncthreads();
    }
    if (tid < nb) bsum[tid] = s[tid] - v;
}

__global__ void scanC_kernel(const int* __restrict__ partial, const int* __restrict__ bsum,
                             int* __restrict__ rp0, int* __restrict__ rp1,
                             int* __restrict__ rp2, int* __restrict__ rp3) {
    int i = blockIdx.x * blockDim.x + threadIdx.x;
    if (i >= LB4) return;
    int g = partial[i] + bsum[i >> 10];
    if (i < LB1)      rp0[i - LB0] = g - CE0;
    else if (i < LB2) rp1[i - LB1] = g - CE1;
    else if (i < LB3) rp2[i - LB2] = g - CE2;
    else              rp3[i - LB3] = g - CE3;
    if (i == 0) {
        rp0[LB1 - LB0] = CE1 - CE0;
        rp1[LB2 - LB1] = CE2 - CE1;
        rp2[LB3 - LB2] = CE3 - CE2;
        rp3[LB4 - LB3] = CE4 - CE3;
    }
}

// scatter only u16 column indices; weights are recomputed from dis at gather time
__global__ void fill_kernel(const int* __restrict__ row, const int* __restrict__ col,
                            const int* __restrict__ rowptr, int* __restrict__ cur,
                            u16* __restrict__ ccol, int E) {
    int e = blockIdx.x * blockDim.x + threadIdx.x;
    if (e >= E) return;
    int r = row[e];
    int pos = rowptr[r] + atomicAdd(&cur[r], 1);
    ccol[pos] = (u16)col[e];
}

// ---------------- fp32 [B][N][3] -> bf16 [N][B][3] transpose-convert ----------------

__global__ void f2b_tr_kernel(const float* __restrict__ in, u16* __restrict__ out, int N) {
    int t = blockIdx.x * blockDim.x + threadIdx.x;   // output-ordered
    if (t >= B_ * N * 3) return;
    int f = t % 3;
    int nb = t / 3;
    int b = nb & 3;
    int n = nb >> 2;
    out[t] = f2b(in[((size_t)b * N + n) * 3 + f]);
}

// ---------------- Chebyshev T-sweep (no GEMM) ----------------
// Batch-interleaved [N][B][F]; thread t -> (r=t>>2, b=t&3).
// FIRST: T1 = L x            (alpha = 1, no self term)
// else:  Tk = 2 L T_{k-1} - T_{k-2}
// edge weight = dis[r]*dis[c], computed on the fly (ccol is u16).
template<int F, bool FIRST>
__global__ __launch_bounds__(128) void sweep_k(
    const u16* __restrict__ gsrc, const u16* __restrict__ selfp, u16* __restrict__ dst,
    const int* __restrict__ rowptr, const u16* __restrict__ ccol,
    const float* __restrict__ dis, int N)
{
    int t = blockIdx.x * 128 + (int)threadIdx.x;
    if (t >= B_ * N) return;
    int r = t >> 2;
    int b = t & 3;

    float tv[F];
    if constexpr (FIRST) {
        #pragma unroll
        for (int f = 0; f < F; ++f) tv[f] = 0.f;
    } else {
        float sv[F];
        load_row_bf16<F>(selfp + (size_t)t * F, sv);
        #pragma unroll
        for (int f = 0; f < F; ++f) tv[f] = -sv[f];
    }
    const float scale = (FIRST ? 1.0f : 2.0f) * dis[r];
    int beg = rowptr[r], end = rowptr[r + 1];
    for (int j = beg; j < end; ++j) {
        int c = (int)ccol[j];
        float w = scale * dis[c];
        float gv[F];
        load_row_bf16<F>(gsrc + (size_t)((c << 2) | b) * F, gv);
        #pragma unroll
        for (int f = 0; f < F; ++f) tv[f] += w * gv[f];
    }
    store_row_bf16<F>(dst + (size_t)t * F, tv);
}

// ---------------- combine: out = sum_k T_k @ W_k (+bias, relu) ----------------
// Reads each T exactly once (coalesced); acc fully in registers.
// OSTD: write fp32 [B][N][G] (final output); else write bf16 interleaved [N][B][G].
template<int F, int G, bool OSTD>
__global__ __launch_bounds__(128) void combine_k(
    const u16* __restrict__ T0, const u16* __restrict__ T1, const u16* __restrict__ T2,
    const u16* __restrict__ T3, const u16* __restrict__ T4, const u16* __restrict__ T5,
    const float* __restrict__ W6, const float* __restrict__ bias,
    u16* __restrict__ outb, float* __restrict__ outf, int N, int relu)
{
    __shared__ float sW[6 * F * G];
    for (int i = threadIdx.x; i < 6 * F * G; i += 128) sW[i] = W6[i];
    __syncthreads();
    int t = blockIdx.x * 128 + (int)threadIdx.x;
    if (t >= B_ * N) return;

    float acc[G];
    #pragma unroll
    for (int g = 0; g < G; ++g) acc[g] = 0.f;

    const u16* Ts[6] = {T0, T1, T2, T3, T4, T5};
    #pragma unroll
    for (int k = 0; k < 6; ++k) {
        float tv[F];
        load_row_bf16<F>(Ts[k] + (size_t)t * F, tv);
        const float* w = sW + k * F * G;
        #pragma unroll
        for (int f = 0; f < F; ++f) {
            float x = tv[f];
            #pragma unroll
            for (int g = 0; g < G; ++g) acc[g] += x * w[f * G + g];
        }
    }
    if (bias) {
        #pragma unroll
        for (int g = 0; g < G; ++g) acc[g] += bias[g];
    }
    if (relu) {
        #pragma unroll
        for (int g = 0; g < G; ++g) acc[g] = fmaxf(acc[g], 0.f);
    }
    if (OSTD) {
        int r = t >> 2, b = t & 3;
        float* orow = outf + ((size_t)b * N + r) * G;
        #pragma unroll
        for (int g = 0; g < G; ++g) orow[g] = acc[g];
    } else {
        store_row_bf16<G>(outb + (size_t)t * G, acc);
    }
}

// ---------------- pool / dense (bf16 interleaved [N][B][F]) ----------------

__global__ void pool_kernel(const u16* __restrict__ in, u16* __restrict__ out,
                            const int* __restrict__ idx, const float* __restrict__ w,
                            int Nout, int F) {
    int t = blockIdx.x * blockDim.x + threadIdx.x;
    if (t >= B_ * Nout * F) return;
    int f = t % F;
    int nb = t / F;
    int b = nb & 3;
    int n = nb >> 2;
    float acc = 0.f;
    for (int k = 0; k < 3; ++k) {
        int src = idx[n * 3 + k];
        acc += w[n * 3 + k] * b2f(in[(size_t)((src << 2) | b) * F + f]);
    }
    out[t] = f2b(acc);
}

// h bf16 interleaved [256][4][32]; logical h[b, i], i = n*32+f
__global__ void dense_enc_kernel(const u16* __restrict__ h, const float* __restrict__ W,
                                 const float* __restrict__ bias, float* __restrict__ z) {
    int b = blockIdx.x >> 6;
    int g = blockIdx.x & 63;
    int tid = threadIdx.x;
    float acc = 0.f;
    for (int i = tid; i < 8192; i += 256) {
        int n = i >> 5, f = i & 31;
        acc += b2f(h[(((size_t)n << 2) | b) * 32 + f]) * W[(size_t)i * 64 + g];
    }
    __shared__ float red[256];
    red[tid] = acc;
    __syncthreads();
    for (int sft = 128; sft > 0; sft >>= 1) {
        if (tid < sft) red[tid] += red[tid + sft];
        __syncthreads();
    }
    if (tid == 0) z[b * 64 + g] = fmaxf(red[0] + bias[g], 0.f);
}

// out bf16 interleaved [256][4][32]
__global__ void dense_dec_kernel(const float* __restrict__ z, const float* __restrict__ W,
                                 const float* __restrict__ bias, u16* __restrict__ out) {
    int t = blockIdx.x * blockDim.x + threadIdx.x;
    if (t >= B_ * 8192) return;
    int b = t / 8192, j = t % 8192;
    float acc = bias[j];
    for (int k = 0; k < 64; ++k) acc += z[b * 64 + k] * W[(size_t)k * 8192 + j];
    int n = j >> 5, f = j & 31;
    out[(((size_t)n << 2) | b) * 32 + f] = f2b(fmaxf(acc, 0.f));
}

// ---------------- host ----------------

static inline unsigned cdivu(size_t a, size_t b) { return (unsigned)((a + b - 1) / b); }

template<int F, int G, bool OSTD = false>
static void run_cheb(const u16* X, u16* const* T, const float* Wk, const float* bias,
                     int relu, u16* outb, float* outf,
                     const int* rp, const u16* cc, const float* dis, int N, hipStream_t s) {
    unsigned g = (unsigned)((size_t)B_ * N / 128);
    sweep_k<F, true><<<g, 128, 0, s>>>(X, nullptr, T[0], rp, cc, dis, N);
    sweep_k<F, false><<<g, 128, 0, s>>>(T[0], X, T[1], rp, cc, dis, N);
    sweep_k<F, false><<<g, 128, 0, s>>>(T[1], T[0], T[2], rp, cc, dis, N);
    sweep_k<F, false><<<g, 128, 0, s>>>(T[2], T[1], T[3], rp, cc, dis, N);
    sweep_k<F, false><<<g, 128, 0, s>>>(T[3], T[2], T[4], rp, cc, dis, N);
    combine_k<F, G, OSTD><<<g, 128, 0, s>>>(X, T[0], T[1], T[2], T[3], T[4],
                                            Wk, bias, outb, outf, N, relu);
}

extern "C" void kernel_launch(void* const* d_in, const int* in_sizes, int n_in,
                              void* d_out, int out_size, void* d_ws, size_t ws_size,
                              hipStream_t stream) {
    (void)in_sizes; (void)n_in; (void)out_size; (void)ws_size;
    hipStream_t s = stream;

    static const int NS_[5] = {65536, 16384, 4096, 1024, 256};
    static const int LBa[5] = {LB0, LB1, LB2, LB3, LB4};
    static const int CEa[5] = {CE0, CE1, CE2, CE3, CE4};

    const float* x = (const float*)d_in[0];
    const int* ei[4];
    for (int l = 0; l < 4; ++l) ei[l] = (const int*)d_in[1 + l];
    const int* down_i[4]; const float* down_w[4];
    const int* up_i[4];   const float* up_w[4];
    for (int i = 0; i < 4; ++i) {
        down_i[i] = (const int*)d_in[6 + 4 * i];
        down_w[i] = (const float*)d_in[7 + 4 * i];
        up_i[i]   = (const int*)d_in[8 + 4 * i];
        up_w[i]   = (const float*)d_in[9 + 4 * i];
    }
    const float* encW[4]; const float* encB[4];
    for (int i = 0; i < 4; ++i) {
        encW[i] = (const float*)d_in[22 + 2 * i];
        encB[i] = (const float*)d_in[23 + 2 * i];
    }
    const float* decW[5];
    for (int i = 0; i < 5; ++i) decW[i] = (const float*)d_in[30 + i];
    const float* decB[4];
    for (int i = 0; i < 4; ++i) decB[i] = (const float*)d_in[35 + i];
    const float* enc_w = (const float*)d_in[39];
    const float* enc_b = (const float*)d_in[40];
    const float* dec_w = (const float*)d_in[41];
    const float* dec_b = (const float*)d_in[42];

    // ---- workspace layout (float units) ----
    float* ws = (float*)d_ws;
    size_t off = 0;
    const size_t HSLOT = (size_t)B_ * 65536 * 16 / 2;   // bf16 buffer = 2,097,152 floats (8.4 MB)
    u16* XA = (u16*)(ws + off); off += HSLOT;
    u16* XBuf = (u16*)(ws + off); off += HSLOT;
    u16* T[5];
    for (int i = 0; i < 5; ++i) { T[i] = (u16*)(ws + off); off += HSLOT; }
    int* cntAll = (int*)(ws + off); off += LB4;
    int* curAll = (int*)(ws + off); off += LB4;
    int* partial = (int*)(ws + off); off += LB4;
    int* bsum = (int*)(ws + off); off += 128;
    float* disAll = ws + off; off += LB4;
    int* rowptr[4];
    for (int l = 0; l < 4; ++l) { rowptr[l] = (int*)(ws + off); off += (size_t)NS_[l] + 4; }
    u16* ccolAll = (u16*)(ws + off); off += (CE4 + 1) / 2;
    float* zbuf = ws + off; off += 256;

    // ---- build CSR + norms for levels 0..3 ----
    hipMemsetAsync(cntAll, 0, (size_t)LB4 * sizeof(int), s);
    hipMemsetAsync(curAll, 0, (size_t)LB4 * sizeof(int), s);
    for (int l = 0; l < 4; ++l) {
        int E = DEG_ * NS_[l];
        cnt_kernel<<<cdivu(E, TPB), TPB, 0, s>>>(ei[l], cntAll + LBa[l], E);
    }
    dis_kernel<<<cdivu(LB4, TPB), TPB, 0, s>>>(cntAll, disAll, LB4);
    scanA_kernel<<<85, 256, 0, s>>>(cntAll, partial, bsum);
    scanB_kernel<<<1, 128, 0, s>>>(bsum, 85);
    scanC_kernel<<<cdivu(LB4, TPB), TPB, 0, s>>>(partial, bsum,
                                                 rowptr[0], rowptr[1], rowptr[2], rowptr[3]);
    for (int l = 0; l < 4; ++l) {
        int E = DEG_ * NS_[l];
        fill_kernel<<<cdivu(E, TPB), TPB, 0, s>>>(ei[l], ei[l] + E, rowptr[l],
                                                  curAll + LBa[l], ccolAll + CEa[l], E);
    }

    const float* dis[4]; const u16* cc[4];
    for (int l = 0; l < 4; ++l) { dis[l] = disAll + LBa[l]; cc[l] = ccolAll + CEa[l]; }

    // ---- encoder ----
    f2b_tr_kernel<<<cdivu((size_t)B_ * 65536 * 3, TPB), TPB, 0, s>>>(x, XA, 65536);
    run_cheb<3, 16>(XA, T, encW[0], encB[0], 1, XBuf, nullptr,
                    rowptr[0], cc[0], dis[0], NS_[0], s);
    pool_kernel<<<cdivu((size_t)B_ * NS_[1] * 16, TPB), TPB, 0, s>>>(
        XBuf, XA, down_i[0], down_w[0], NS_[1], 16);
    run_cheb<16, 16>(XA, T, encW[1], encB[1], 1, XBuf, nullptr,
                     rowptr[1], cc[1], dis[1], NS_[1], s);
    pool_kernel<<<cdivu((size_t)B_ * NS_[2] * 16, TPB), TPB, 0, s>>>(
        XBuf, XA, down_i[1], down_w[1], NS_[2], 16);
    run_cheb<16, 16>(XA, T, encW[2], encB[2], 1, XBuf, nullptr,
                     rowptr[2], cc[2], dis[2], NS_[2], s);
    pool_kernel<<<cdivu((size_t)B_ * NS_[3] * 16, TPB), TPB, 0, s>>>(
        XBuf, XA, down_i[2], down_w[2], NS_[3], 16);
    run_cheb<16, 32>(XA, T, encW[3], encB[3], 1, XBuf, nullptr,
                     rowptr[3], cc[3], dis[3], NS_[3], s);
    pool_kernel<<<cdivu((size_t)B_ * NS_[4] * 32, TPB), TPB, 0, s>>>(
        XBuf, XA, down_i[3], down_w[3], NS_[4], 32);

    // ---- latent ----
    dense_enc_kernel<<<B_ * 64, 256, 0, s>>>(XA, enc_w, enc_b, zbuf);
    dense_dec_kernel<<<cdivu((size_t)B_ * 8192, TPB), TPB, 0, s>>>(zbuf, dec_w, dec_b, XBuf);

    // ---- decoder ----
    pool_kernel<<<cdivu((size_t)B_ * NS_[3] * 32, TPB), TPB, 0, s>>>(
        XBuf, XA, up_i[3], up_w[3], NS_[3], 32);
    run_cheb<32, 16>(XA, T, decW[0], decB[0], 1, XBuf, nullptr,
                     rowptr[3], cc[3], dis[3], NS_[3], s);
    pool_kernel<<<cdivu((size_t)B_ * NS_[2] * 16, TPB), TPB, 0, s>>>(
        XBuf, XA, up_i[2], up_w[2], NS_[2], 16);
    run_cheb<16, 16>(XA, T, decW[1], decB[1], 1, XBuf, nullptr,
                     rowptr[2], cc[2], dis[2], NS_[2], s);
    pool_kernel<<<cdivu((size_t)B_ * NS_[1] * 16, TPB), TPB, 0, s>>>(
        XBuf, XA, up_i[1], up_w[1], NS_[1], 16);
    run_cheb<16, 16>(XA, T, decW[2], decB[2], 1, XBuf, nullptr,
                     rowptr[1], cc[1], dis[1], NS_[1], s);
    pool_kernel<<<cdivu((size_t)B_ * NS_[0] * 16, TPB), TPB, 0, s>>>(
        XBuf, XA, up_i[0], up_w[0], NS_[0], 16);
    run_cheb<16, 16>(XA, T, decW[3], decB[3], 1, XBuf, nullptr,
                     rowptr[0], cc[0], dis[0], NS_[0], s);
    // final conv: 16 -> 3, no bias/relu, fp32 -> d_out in canonical [B][N][3]
    run_cheb<16, 3, true>(XBuf, T, decW[4], nullptr, 0, nullptr, (float*)d_out,
                          rowptr[0], cc[0], dis[0], NS_[0], s);
}